// Round 3
// baseline (6861.687 us; speedup 1.0000x reference)
//
#include <hip/hip_runtime.h>
#include <math.h>

#define EPS_BN 1e-5f
#define NEG_INF (-1e30f)

constexpr int NPTS = 2048;
constexpr int KNB = 20;

// ---------------------------------------------------------------------------
// kNN: one block per (b, n). Compute pd[m] = 2*dot(xn,xm) - d2n - d2m in LDS,
// then 20 iterations of argmax (tie-break: lowest index, matching lax.top_k).
// Exactness: for m==n, dot/d2m/d2n accumulate in identical order -> pd==0.
// ---------------------------------------------------------------------------
template<int C>
__global__ void knn_kernel(const float* __restrict__ X, int ld, int coff,
                           int* __restrict__ idx) {
  const int n = blockIdx.x, b = blockIdx.y;
  const int tid = threadIdx.x;
  const float* Xb = X + (size_t)b * NPTS * ld + coff;

  __shared__ float xn[(C < 4) ? 4 : C];
  __shared__ float pd[NPTS];
  __shared__ float rv[256];
  __shared__ int   ri[256];

  for (int c = tid; c < C; c += 256) xn[c] = Xb[(size_t)n * ld + c];
  __syncthreads();

  float d2n = 0.f;
  if constexpr (C % 4 == 0) {
    const float4* xn4 = (const float4*)xn;
    for (int c4 = 0; c4 < C / 4; ++c4) {
      float4 u = xn4[c4];
      d2n += u.x * u.x; d2n += u.y * u.y; d2n += u.z * u.z; d2n += u.w * u.w;
    }
  } else {
    for (int c = 0; c < C; ++c) d2n += xn[c] * xn[c];
  }

  for (int m = tid; m < NPTS; m += 256) {
    const float* xm = Xb + (size_t)m * ld;
    float dot = 0.f, d2m = 0.f;
    if constexpr (C % 4 == 0) {
      const float4* xm4 = (const float4*)xm;
      const float4* xn4 = (const float4*)xn;
      for (int c4 = 0; c4 < C / 4; ++c4) {
        float4 v = xm4[c4], u = xn4[c4];
        dot += u.x * v.x; dot += u.y * v.y; dot += u.z * v.z; dot += u.w * v.w;
        d2m += v.x * v.x; d2m += v.y * v.y; d2m += v.z * v.z; d2m += v.w * v.w;
      }
    } else {
      for (int c = 0; c < C; ++c) { float v = xm[c]; dot += xn[c] * v; d2m += v * v; }
    }
    pd[m] = 2.f * dot - d2n - d2m;
  }
  __syncthreads();

  int* out = idx + ((size_t)b * NPTS + n) * KNB;
  for (int k = 0; k < KNB; ++k) {
    float bv = NEG_INF; int bi = NPTS;
    for (int m = tid; m < NPTS; m += 256) {
      float v = pd[m];
      if (v > bv || (v == bv && m < bi)) { bv = v; bi = m; }
    }
    rv[tid] = bv; ri[tid] = bi;
    __syncthreads();
    for (int s = 128; s > 0; s >>= 1) {
      if (tid < s) {
        float ov = rv[tid + s]; int oi = ri[tid + s];
        if (ov > rv[tid] || (ov == rv[tid] && oi < ri[tid])) { rv[tid] = ov; ri[tid] = oi; }
      }
      __syncthreads();
    }
    if (tid == 0) { out[k] = ri[0]; pd[ri[0]] = NEG_INF; }
    __syncthreads();
  }
}

// ---------------------------------------------------------------------------
// EdgeConv: one block per (b, n), blockDim = O (one output channel/thread).
// h_k[o] = dot(W1[o], nbr_k) + cterm[o];  cterm = dot(W2[o]-W1[o], ctr).
// max over k, then BN (+scale guaranteed >0) + LeakyReLU applied once.
// k kept in registers (h[20]) so each W element is read once per thread.
// ---------------------------------------------------------------------------
template<int C, int O>
__global__ void edgeconv_kernel(const float* __restrict__ X, int ldx, int coff,
                                const int* __restrict__ idx,
                                const float* __restrict__ W,   // [O][2C]
                                const float* __restrict__ bnp, // [4][O]
                                float* __restrict__ Y, int ldy, int yoff) {
  const int n = blockIdx.x, b = blockIdx.y;
  const int tid = threadIdx.x;
  const float* Xb = X + (size_t)b * NPTS * ldx + coff;

  __shared__ float xn[(C < 4) ? 4 : C];
  __shared__ float nbr[KNB][(C < 4) ? 4 : C];
  __shared__ int ids[KNB];

  if (tid < KNB) ids[tid] = idx[((size_t)b * NPTS + n) * KNB + tid];
  for (int c = tid; c < C; c += O) xn[c] = Xb[(size_t)n * ldx + c];
  __syncthreads();
  for (int t = tid; t < KNB * C; t += O) {
    int k = t / C, c = t - k * C;
    nbr[k][c] = Xb[(size_t)ids[k] * ldx + c];
  }
  __syncthreads();

  const float* Wo = W + (size_t)tid * (2 * C);
  float h[KNB];
  float cterm = 0.f;
  if constexpr (C % 4 == 0) {
    const float4* W1 = (const float4*)Wo;
    const float4* W2 = (const float4*)(Wo + C);
    const float4* xn4 = (const float4*)xn;
    for (int c4 = 0; c4 < C / 4; ++c4) {
      float4 a = W1[c4], bb = W2[c4], u = xn4[c4];
      cterm += (bb.x - a.x) * u.x + (bb.y - a.y) * u.y +
               (bb.z - a.z) * u.z + (bb.w - a.w) * u.w;
    }
    #pragma unroll
    for (int k = 0; k < KNB; ++k) h[k] = cterm;
    for (int c4 = 0; c4 < C / 4; ++c4) {
      float4 a = W1[c4];
      #pragma unroll
      for (int k = 0; k < KNB; ++k) {
        float4 v = ((const float4*)nbr[k])[c4];
        h[k] += a.x * v.x + a.y * v.y + a.z * v.z + a.w * v.w;
      }
    }
  } else {
    for (int c = 0; c < C; ++c) cterm += (Wo[C + c] - Wo[c]) * xn[c];
    #pragma unroll
    for (int k = 0; k < KNB; ++k) h[k] = cterm;
    for (int c = 0; c < C; ++c) {
      float a = Wo[c];
      #pragma unroll
      for (int k = 0; k < KNB; ++k) h[k] += a * nbr[k][c];
    }
  }
  float hmax = NEG_INF;
  #pragma unroll
  for (int k = 0; k < KNB; ++k) hmax = fmaxf(hmax, h[k]);

  float gg = bnp[tid], be = bnp[O + tid], mm = bnp[2 * O + tid], vv = bnp[3 * O + tid];
  float s = gg / sqrtf(vv + EPS_BN);
  float y = (hmax - mm) * s + be;
  Y[((size_t)b * NPTS + n) * ldy + yoff + tid] = (y > 0.f) ? y : 0.2f * y;
}

// ---------------------------------------------------------------------------
// x5 = act(bn5(xc @ w5^T)) fused with per-tile max/sum over the 16 staged rows.
// Block: (tile of 16 points, b), 256 threads; each thread does 4 output chans.
// ---------------------------------------------------------------------------
__global__ void x5_kernel(const float* __restrict__ XC,   // [B][N][512]
                          const float* __restrict__ W5,   // [1024][512]
                          const float* __restrict__ bnp,  // [4][1024]
                          float* __restrict__ pmax,       // [B][128][1024]
                          float* __restrict__ psum) {
  const int b = blockIdx.y, tile = blockIdx.x;
  const int t0 = tile * 16;
  const int tid = threadIdx.x;
  __shared__ float rows[16][512];
  for (int t = tid; t < 16 * 512; t += 256) {
    int i = t >> 9, c = t & 511;
    rows[i][c] = XC[((size_t)b * NPTS + t0 + i) * 512 + c];
  }
  __syncthreads();
  for (int og = 0; og < 4; ++og) {
    const int o = og * 256 + tid;
    const float4* w = (const float4*)(W5 + (size_t)o * 512);
    float acc[16];
    #pragma unroll
    for (int i = 0; i < 16; ++i) acc[i] = 0.f;
    for (int c4 = 0; c4 < 128; ++c4) {
      float4 wv = w[c4];
      #pragma unroll
      for (int i = 0; i < 16; ++i) {
        float4 r = ((const float4*)rows[i])[c4];
        acc[i] += wv.x * r.x + wv.y * r.y + wv.z * r.z + wv.w * r.w;
      }
    }
    float gg = bnp[o], be = bnp[1024 + o], mm = bnp[2048 + o], vv = bnp[3072 + o];
    float s = gg / sqrtf(vv + EPS_BN);
    float vmax = NEG_INF, vsum = 0.f;
    #pragma unroll
    for (int i = 0; i < 16; ++i) {
      float y = (acc[i] - mm) * s + be;
      y = (y > 0.f) ? y : 0.2f * y;
      vmax = fmaxf(vmax, y);
      vsum += y;
    }
    pmax[((size_t)b * 128 + tile) * 1024 + o] = vmax;
    psum[((size_t)b * 128 + tile) * 1024 + o] = vsum;
  }
}

__global__ void x5_reduce_final(const float* __restrict__ pmax,
                                const float* __restrict__ psum,
                                float* __restrict__ g) {  // [B][2048]: max|mean
  const int b = blockIdx.y;
  const int o = blockIdx.x * 256 + threadIdx.x;
  float vmax = NEG_INF, vsum = 0.f;
  for (int t = 0; t < 128; ++t) {
    vmax = fmaxf(vmax, pmax[((size_t)b * 128 + t) * 1024 + o]);
    vsum += psum[((size_t)b * 128 + t) * 1024 + o];
  }
  g[(size_t)b * 2048 + o] = vmax;
  g[(size_t)b * 2048 + 1024 + o] = vsum * (1.f / 2048.f);
}

// ---------------------------------------------------------------------------
// Final MLP (tiny; B=8 blocks each)
// ---------------------------------------------------------------------------
__global__ void mlp1_kernel(const float* __restrict__ g, const float* __restrict__ W, // [512][2048]
                            const float* __restrict__ bnp, float* __restrict__ h1) {
  const int b = blockIdx.x, tid = threadIdx.x; // 512 threads
  __shared__ float row[2048];
  for (int c = tid; c < 2048; c += 512) row[c] = g[(size_t)b * 2048 + c];
  __syncthreads();
  const float4* w = (const float4*)(W + (size_t)tid * 2048);
  float acc = 0.f;
  for (int c4 = 0; c4 < 512; ++c4) {
    float4 wv = w[c4], rv = ((const float4*)row)[c4];
    acc += wv.x * rv.x + wv.y * rv.y + wv.z * rv.z + wv.w * rv.w;
  }
  float gg = bnp[tid], be = bnp[512 + tid], mm = bnp[1024 + tid], vv = bnp[1536 + tid];
  float y = (acc - mm) * (gg / sqrtf(vv + EPS_BN)) + be;
  h1[(size_t)b * 512 + tid] = (y > 0.f) ? y : 0.2f * y;
}

__global__ void mlp2_kernel(const float* __restrict__ h1, const float* __restrict__ W, // [256][512]
                            const float* __restrict__ bl, const float* __restrict__ bnp,
                            float* __restrict__ h2) {
  const int b = blockIdx.x, tid = threadIdx.x; // 256 threads
  __shared__ float row[512];
  for (int c = tid; c < 512; c += 256) row[c] = h1[(size_t)b * 512 + c];
  __syncthreads();
  const float4* w = (const float4*)(W + (size_t)tid * 512);
  float acc = 0.f;
  for (int c4 = 0; c4 < 128; ++c4) {
    float4 wv = w[c4], rv = ((const float4*)row)[c4];
    acc += wv.x * rv.x + wv.y * rv.y + wv.z * rv.z + wv.w * rv.w;
  }
  acc += bl[tid];
  float gg = bnp[tid], be = bnp[256 + tid], mm = bnp[512 + tid], vv = bnp[768 + tid];
  float y = (acc - mm) * (gg / sqrtf(vv + EPS_BN)) + be;
  h2[(size_t)b * 256 + tid] = (y > 0.f) ? y : 0.2f * y;
}

__global__ void mlp3_kernel(const float* __restrict__ h2, const float* __restrict__ W, // [40][256]
                            const float* __restrict__ bl, float* __restrict__ out) {
  const int b = blockIdx.x, tid = threadIdx.x; // 64 threads
  __shared__ float row[256];
  for (int c = tid; c < 256; c += 64) row[c] = h2[(size_t)b * 256 + c];
  __syncthreads();
  if (tid < 40) {
    float acc = 0.f;
    for (int c = 0; c < 256; ++c) acc += W[tid * 256 + c] * row[c];
    out[(size_t)b * 40 + tid] = acc + bl[tid];
  }
}

// ---------------------------------------------------------------------------
extern "C" void kernel_launch(void* const* d_in, const int* in_sizes, int n_in,
                              void* d_out, int out_size, void* d_ws, size_t ws_size,
                              hipStream_t stream) {
  const float* x   = (const float*)d_in[0];
  // d_in[1] = normal (unused on this path)
  const float* w1  = (const float*)d_in[2];
  const float* w2  = (const float*)d_in[3];
  const float* w3  = (const float*)d_in[4];
  const float* w4  = (const float*)d_in[5];
  const float* w5  = (const float*)d_in[6];
  const float* wl1 = (const float*)d_in[7];
  const float* wl2 = (const float*)d_in[8];
  const float* bl2 = (const float*)d_in[9];
  const float* wl3 = (const float*)d_in[10];
  const float* bl3 = (const float*)d_in[11];
  const float* bn1 = (const float*)d_in[12];
  const float* bn2 = (const float*)d_in[13];
  const float* bn3 = (const float*)d_in[14];
  const float* bn4 = (const float*)d_in[15];
  const float* bn5 = (const float*)d_in[16];
  const float* bn6 = (const float*)d_in[17];
  const float* bn7 = (const float*)d_in[18];
  float* out = (float*)d_out;

  char* ws = (char*)d_ws;
  // xc: [8][2048][512] f32 = 32 MiB (holds x1|x2|x3|x4 channel slices)
  float* xc   = (float*)(ws);
  int*   idx  = (int*)  (ws + 33554432);             // [8][2048][20]  = 1.25 MiB
  float* pmax = (float*)(ws + 33554432 + 1310720);   // [8][128][1024] = 4 MiB
  float* psum = (float*)(ws + 33554432 + 1310720 + 4194304);
  float* g    = (float*)(ws + 33554432 + 1310720 + 8388608);          // [8][2048]
  float* h1   = (float*)(ws + 33554432 + 1310720 + 8388608 + 65536);  // [8][512]
  float* h2   = (float*)(ws + 33554432 + 1310720 + 8388608 + 65536 + 16384); // [8][256]

  dim3 gridBN(NPTS, 8);

  // EdgeConv 1: x[.,.,3] -> xc[:, :, 0:64]
  knn_kernel<3><<<gridBN, 256, 0, stream>>>(x, 3, 0, idx);
  edgeconv_kernel<3, 64><<<gridBN, 64, 0, stream>>>(x, 3, 0, idx, w1, bn1, xc, 512, 0);
  // EdgeConv 2: x1 -> xc[:, :, 64:128]
  knn_kernel<64><<<gridBN, 256, 0, stream>>>(xc, 512, 0, idx);
  edgeconv_kernel<64, 64><<<gridBN, 64, 0, stream>>>(xc, 512, 0, idx, w2, bn2, xc, 512, 64);
  // EdgeConv 3: x2 -> xc[:, :, 128:256]
  knn_kernel<64><<<gridBN, 256, 0, stream>>>(xc, 512, 64, idx);
  edgeconv_kernel<64, 128><<<gridBN, 128, 0, stream>>>(xc, 512, 64, idx, w3, bn3, xc, 512, 128);
  // EdgeConv 4: x3 -> xc[:, :, 256:512]
  knn_kernel<128><<<gridBN, 256, 0, stream>>>(xc, 512, 128, idx);
  edgeconv_kernel<128, 256><<<gridBN, 256, 0, stream>>>(xc, 512, 128, idx, w4, bn4, xc, 512, 256);

  // x5 GEMM + bn + act + fused partial max/mean
  x5_kernel<<<dim3(128, 8), 256, 0, stream>>>(xc, w5, bn5, pmax, psum);
  x5_reduce_final<<<dim3(4, 8), 256, 0, stream>>>(pmax, psum, g);

  // Final MLP
  mlp1_kernel<<<8, 512, 0, stream>>>(g, wl1, bn6, h1);
  mlp2_kernel<<<8, 256, 0, stream>>>(h1, wl2, bl2, bn7, h2);
  mlp3_kernel<<<8, 64, 0, stream>>>(h2, wl3, bl3, out);
}